// Round 1
// baseline (1292.359 us; speedup 1.0000x reference)
//
#include <hip/hip_runtime.h>
#include <hip/hip_bf16.h>
#include <math.h>

#define T_TOK 1024
#define H_DIM 1024
#define I_DIM 512
#define E_NUM 64
#define K_TOP 8
#define TM 32
#define TN 128
#define TK 32
#define MAX_TILES 352   // sum ceil(n_e/32) <= 8192/32 + 64 = 320 routed, + 32 shared

// ---------------- router: one wave per token, lane = expert ----------------
__global__ __launch_bounds__(64) void router_kernel(
    const float* __restrict__ x, const float* __restrict__ rw,
    int* __restrict__ topk_idx, float* __restrict__ topk_w, int* __restrict__ counts)
{
  int t = blockIdx.x;
  int lane = threadIdx.x;
  const float* xr = x + (size_t)t * H_DIM;
  float acc = 0.f;
  for (int h = 0; h < H_DIM; ++h)
    acc = fmaf(xr[h], rw[(size_t)h * E_NUM + lane], acc);
  float aff = 1.f / (1.f + expf(-acc));   // sigmoid
  float v = aff;
  float vals[K_TOP]; int idxs[K_TOP];
  for (int k = 0; k < K_TOP; ++k) {
    float bv = v; int bi = lane;
    #pragma unroll
    for (int off = 32; off > 0; off >>= 1) {
      float ov = __shfl_down(bv, off);
      int   oi = __shfl_down(bi, off);
      if (ov > bv || (ov == bv && oi < bi)) { bv = ov; bi = oi; }  // jax tie: lower idx
    }
    bv = __shfl(bv, 0); bi = __shfl(bi, 0);
    vals[k] = bv; idxs[k] = bi;
    if (lane == bi) v = -1.f;  // affinities in (0,1): -1 is below all
  }
  if (lane == 0) {
    float s = 0.f;
    for (int k = 0; k < K_TOP; ++k) s += vals[k];
    float inv = 1.f / (s + 1e-9f);
    for (int k = 0; k < K_TOP; ++k) {
      topk_idx[t * K_TOP + k] = idxs[k];
      topk_w[t * K_TOP + k] = vals[k] * inv;
      atomicAdd(&counts[idxs[k]], 1);
    }
  }
}

// ---------------- scan + tile table (serial on lane 0; 65 entries) ----------------
__global__ void scan_tiles_kernel(int* counts, int* offsets, int* n_tiles,
                                  int* te, int* ts, int* tl)
{
  if (threadIdx.x == 0 && blockIdx.x == 0) {
    counts[E_NUM] = T_TOK;  // shared expert: all tokens
    int off = 0;
    for (int e = 0; e <= E_NUM; ++e) { offsets[e] = off; off += counts[e]; }
    offsets[E_NUM + 1] = off;
    int nt = 0;
    for (int e = 0; e <= E_NUM; ++e) {
      int c = counts[e], s = offsets[e];
      for (int i = 0; i < c; i += TM) {
        te[nt] = e; ts[nt] = s + i; tl[nt] = (c - i < TM) ? (c - i) : TM; nt++;
      }
    }
    *n_tiles = nt;
  }
}

// ---------------- fill grouped pair lists ----------------
__global__ __launch_bounds__(256) void fill_pairs_kernel(
    const int* __restrict__ topk_idx, const float* __restrict__ topk_w,
    const int* __restrict__ offsets, int* __restrict__ cursor,
    int* __restrict__ pair_token, float* __restrict__ pair_w)
{
  int tid = blockIdx.x * 256 + threadIdx.x;
  if (tid < T_TOK * K_TOP) {
    int t = tid >> 3;
    int e = topk_idx[tid];
    int pos = atomicAdd(&cursor[e], 1);
    int idx = offsets[e] + pos;
    pair_token[idx] = t;
    pair_w[idx] = topk_w[tid];
  } else if (tid < T_TOK * K_TOP + T_TOK) {
    int t = tid - T_TOK * K_TOP;
    pair_token[T_TOK * K_TOP + t] = t;  // offsets[64] == 8192 always
    pair_w[T_TOK * K_TOP + t] = 1.0f;
  }
}

// ---------------- stage A: act = silu(x@Wg) * (x@Wu) * w  [per expert tile] ----------------
__global__ __launch_bounds__(256) void stage_a_kernel(
    const float* __restrict__ x,
    const float* __restrict__ eg, const float* __restrict__ eu,
    const float* __restrict__ sg, const float* __restrict__ su,
    const int* __restrict__ te, const int* __restrict__ ts, const int* __restrict__ tl,
    const int* __restrict__ n_tiles,
    const int* __restrict__ pair_token, const float* __restrict__ pair_w,
    float* __restrict__ act)
{
  int tile = blockIdx.x;
  if (tile >= *n_tiles) return;
  int e = te[tile];
  int pstart = ts[tile];
  int plen = tl[tile];
  int i0 = blockIdx.y * TN;
  const float* Wg = (e < E_NUM) ? eg + (size_t)e * H_DIM * I_DIM : sg;
  const float* Wu = (e < E_NUM) ? eu + (size_t)e * H_DIM * I_DIM : su;

  __shared__ float Xs[TM][40];   // [row][k], row stride 160B (16B-aligned), pad kills conflicts
  __shared__ float Gs[TK][TN];
  __shared__ float Us[TK][TN];
  __shared__ int   tok_s[TM];
  __shared__ float w_s[TM];

  int tid = threadIdx.x;
  if (tid < TM) {
    tok_s[tid] = pair_token[pstart + tid];  // may read past segment end; memory-safe
    w_s[tid]   = pair_w[pstart + tid];
  }
  __syncthreads();

  int xrow = tid >> 3;
  int xk   = (tid & 7) * 4;
  int xtok = tok_s[xrow];
  int kr = tid >> 5;          // 0..7
  int cq = (tid & 31) * 4;    // 0..124
  int r4 = (tid >> 5) * 4;

  float accg[4][4] = {};
  float accu[4][4] = {};

  for (int k0 = 0; k0 < H_DIM; k0 += TK) {
    float4 xv = *(const float4*)(x + (size_t)xtok * H_DIM + k0 + xk);
    float4 gv[4], uv[4];
    #pragma unroll
    for (int j = 0; j < 4; ++j) {
      gv[j] = *(const float4*)(Wg + (size_t)(k0 + kr + j * 8) * I_DIM + i0 + cq);
      uv[j] = *(const float4*)(Wu + (size_t)(k0 + kr + j * 8) * I_DIM + i0 + cq);
    }
    __syncthreads();
    *(float4*)&Xs[xrow][xk] = xv;
    #pragma unroll
    for (int j = 0; j < 4; ++j) {
      *(float4*)&Gs[kr + j * 8][cq] = gv[j];
      *(float4*)&Us[kr + j * 8][cq] = uv[j];
    }
    __syncthreads();
    #pragma unroll
    for (int k = 0; k < TK; ++k) {
      float a[4];
      #pragma unroll
      for (int i = 0; i < 4; ++i) a[i] = Xs[r4 + i][k];
      float4 bg = *(const float4*)&Gs[k][cq];
      float4 bu = *(const float4*)&Us[k][cq];
      const float* bgp = (const float*)&bg;
      const float* bup = (const float*)&bu;
      #pragma unroll
      for (int i = 0; i < 4; ++i) {
        #pragma unroll
        for (int j = 0; j < 4; ++j) {
          accg[i][j] = fmaf(a[i], bgp[j], accg[i][j]);
          accu[i][j] = fmaf(a[i], bup[j], accu[i][j]);
        }
      }
    }
  }

  #pragma unroll
  for (int i = 0; i < 4; ++i) {
    int row = r4 + i;
    if (row < plen) {
      float wgt = w_s[row];
      float4 o;
      float* op = (float*)&o;
      #pragma unroll
      for (int j = 0; j < 4; ++j) {
        float g = accg[i][j];
        float s = g / (1.f + expf(-g));   // silu
        op[j] = s * accu[i][j] * wgt;
      }
      *(float4*)(act + (size_t)(pstart + row) * I_DIM + i0 + cq) = o;
    }
  }
}

// ---------------- stage B: out[token] += act @ Wd ----------------
__global__ __launch_bounds__(256) void stage_b_kernel(
    const float* __restrict__ act,
    const float* __restrict__ ed, const float* __restrict__ sd,
    const int* __restrict__ te, const int* __restrict__ ts, const int* __restrict__ tl,
    const int* __restrict__ n_tiles,
    const int* __restrict__ pair_token,
    float* __restrict__ out)
{
  int tile = blockIdx.x;
  if (tile >= *n_tiles) return;
  int e = te[tile];
  int pstart = ts[tile];
  int plen = tl[tile];
  int h0 = blockIdx.y * TN;
  const float* Wd = (e < E_NUM) ? ed + (size_t)e * I_DIM * H_DIM : sd;

  __shared__ float As[TM][40];
  __shared__ float Ds[TK][TN];
  __shared__ int   tok_s[TM];

  int tid = threadIdx.x;
  if (tid < TM) tok_s[tid] = pair_token[pstart + tid];

  int arow = tid >> 3;
  int ak   = (tid & 7) * 4;
  int kr = tid >> 5;
  int cq = (tid & 31) * 4;
  int r4 = (tid >> 5) * 4;

  float acc[4][4] = {};

  for (int k0 = 0; k0 < I_DIM; k0 += TK) {
    float4 av = *(const float4*)(act + (size_t)(pstart + arow) * I_DIM + k0 + ak);
    float4 dv[4];
    #pragma unroll
    for (int j = 0; j < 4; ++j)
      dv[j] = *(const float4*)(Wd + (size_t)(k0 + kr + j * 8) * H_DIM + h0 + cq);
    __syncthreads();
    *(float4*)&As[arow][ak] = av;
    #pragma unroll
    for (int j = 0; j < 4; ++j)
      *(float4*)&Ds[kr + j * 8][cq] = dv[j];
    __syncthreads();
    #pragma unroll
    for (int k = 0; k < TK; ++k) {
      float a[4];
      #pragma unroll
      for (int i = 0; i < 4; ++i) a[i] = As[r4 + i][k];
      float4 b = *(const float4*)&Ds[k][cq];
      const float* bp = (const float*)&b;
      #pragma unroll
      for (int i = 0; i < 4; ++i) {
        #pragma unroll
        for (int j = 0; j < 4; ++j)
          acc[i][j] = fmaf(a[i], bp[j], acc[i][j]);
      }
    }
  }

  #pragma unroll
  for (int i = 0; i < 4; ++i) {
    int row = r4 + i;
    if (row < plen) {
      int t = tok_s[row];
      float* op = out + (size_t)t * H_DIM + h0 + cq;
      #pragma unroll
      for (int j = 0; j < 4; ++j)
        atomicAdd(&op[j], acc[i][j]);
    }
  }
}

// ---------------- launch ----------------
extern "C" void kernel_launch(void* const* d_in, const int* in_sizes, int n_in,
                              void* d_out, int out_size, void* d_ws, size_t ws_size,
                              hipStream_t stream) {
  const float* x  = (const float*)d_in[0];
  const float* rw = (const float*)d_in[1];
  const float* sg = (const float*)d_in[2];
  const float* su = (const float*)d_in[3];
  const float* sd = (const float*)d_in[4];
  const float* eg = (const float*)d_in[5];
  const float* eu = (const float*)d_in[6];
  const float* ed = (const float*)d_in[7];
  float* out = (float*)d_out;

  // workspace layout (ints/floats)
  int* counts  = (int*)d_ws;                  // 65
  int* offsets = counts + 65;                 // 66
  int* cursor  = offsets + 66;                // 65
  int* n_tiles = cursor + 65;                 // 1
  int* te = n_tiles + 1;                      // MAX_TILES
  int* ts = te + MAX_TILES;
  int* tl = ts + MAX_TILES;
  int* topk_idx = tl + MAX_TILES;             // 1024*8
  int* pair_token = topk_idx + T_TOK * K_TOP; // 9216
  float* topk_w = (float*)(pair_token + (T_TOK * K_TOP + T_TOK)); // 8192
  float* pair_w = topk_w + T_TOK * K_TOP;     // 9216
  size_t used = (size_t)((char*)(pair_w + (T_TOK * K_TOP + T_TOK)) - (char*)d_ws);
  size_t act_off = (used + 255) & ~(size_t)255;  // 16B-align for float4
  float* act = (float*)((char*)d_ws + act_off);  // 9216 * 512 floats (~18.9 MB)

  // zero control region (counts/offsets/cursor/n_tiles/tile table) and output
  hipMemsetAsync(d_ws, 0, 5120, stream);
  hipMemsetAsync(d_out, 0, (size_t)out_size * sizeof(float), stream);

  router_kernel<<<T_TOK, 64, 0, stream>>>(x, rw, topk_idx, topk_w, counts);
  scan_tiles_kernel<<<1, 64, 0, stream>>>(counts, offsets, n_tiles, te, ts, tl);
  fill_pairs_kernel<<<(T_TOK * K_TOP + T_TOK + 255) / 256, 256, 0, stream>>>(
      topk_idx, topk_w, offsets, cursor, pair_token, pair_w);
  stage_a_kernel<<<dim3(MAX_TILES, I_DIM / TN), 256, 0, stream>>>(
      x, eg, eu, sg, su, te, ts, tl, n_tiles, pair_token, pair_w, act);
  stage_b_kernel<<<dim3(MAX_TILES, H_DIM / TN), 256, 0, stream>>>(
      act, ed, sd, te, ts, tl, n_tiles, pair_token, out);
}